// Round 9
// baseline (2153.883 us; speedup 1.0000x reference)
//
#include <hip/hip_runtime.h>
#include <hip/hip_bf16.h>

// Fused triplane sample + 3-layer MLP (32->128->128->4, ReLU), FP32 out,
// output channels permuted [1,2,3,0]. Reshape semantics: reference's
// sampled(B,C,N).reshape(B,N,C) is a flat reinterpret, so MLP A-row p is
// flat[(p*32)..(p*32+32)) of the (b,channel,n) sample buffer.
// Per 16-row tile t: b=t>>14, c=(t&0x3FFF)>>9, n0=(t&0x1FF)*512;
// lane(l15,quad) samples points n0+l15*32+quad*8+{0..7} at channel c = its
// 16x16x32 A-fragment. ONLY change vs round-7 source: output is float32.

#define C_ 32
#define HW_ (128 * 128)
#define NPTS (4 * 262144)
#define NTILES (NPTS / 16)
#define LDS_S 132             /* LDS row stride in floats */

typedef short s8v __attribute__((ext_vector_type(8)));
typedef float f4v __attribute__((ext_vector_type(4)));
typedef unsigned int u4v __attribute__((ext_vector_type(4)));

__device__ __attribute__((aligned(64))) unsigned short g_planes[3 * HW_ * C_]; // (3,H,W,C) bf16
__device__ __attribute__((aligned(16))) unsigned short g_w0[128 * 32];
__device__ __attribute__((aligned(16))) unsigned short g_w1[128 * 128];
__device__ __attribute__((aligned(16))) unsigned short g_w2[16 * 128];  // perm-baked, padded
__device__ float g_b0[128];
__device__ float g_b1[128];
__device__ float g_b2p[16];

template <typename TO, typename FROM>
static __device__ __forceinline__ TO bitc(FROM f) {
    union { FROM a; TO b; } u; u.a = f; return u.b;
}

// MFMA operand-type shim (v8i16 vs v8bf16 builtin signature) -- proven to run.
template <typename V>
static __device__ __forceinline__ auto mfma_k32(V a, V b, f4v c, int)
    -> decltype(__builtin_amdgcn_mfma_f32_16x16x32_bf16(a, b, c, 0, 0, 0)) {
    return __builtin_amdgcn_mfma_f32_16x16x32_bf16(a, b, c, 0, 0, 0);
}
template <typename V>
static __device__ __forceinline__ f4v mfma_k32(V a, V b, f4v c, long) {
    typedef __bf16 b8v __attribute__((ext_vector_type(8)));
    return __builtin_amdgcn_mfma_f32_16x16x32_bf16(bitc<b8v>(a), bitc<b8v>(b), c, 0, 0, 0);
}
static __device__ __forceinline__ f4v MFMA(s8v a, s8v b, f4v c) {
    return mfma_k32(a, b, c, 0);
}

__device__ __forceinline__ unsigned short f2bf(float f) {
    union { float f; unsigned int i; } v; v.f = f;
    unsigned int r = v.i + 0x7FFFu + ((v.i >> 16) & 1u);
    return (unsigned short)(r >> 16);
}

// ---- prep: planes (3C,H,W) fp32 -> (3,H,W,C) bf16 ---------------------------
__global__ void prep_planes_k(const float* __restrict__ tp) {
    int o = blockIdx.x * 256 + threadIdx.x;   // 1572864 threads
    if (o >= 3 * HW_ * C_) return;
    int c  = o & 31;
    int xy = (o >> 5) & (HW_ - 1);
    int pl = o >> 19;
    g_planes[o] = f2bf(tp[(pl * C_ + c) * HW_ + xy]);
}

// ---- prep: weights/biases -> bf16; w2/b2 permuted [1,2,3,0], padded ---------
__global__ void prep_weights_k(const float* __restrict__ w0, const float* __restrict__ b0,
                               const float* __restrict__ w1, const float* __restrict__ b1,
                               const float* __restrict__ w2, const float* __restrict__ b2) {
    int i = blockIdx.x * 256 + threadIdx.x;   // 16384 threads
    if (i < 128 * 32)  g_w0[i] = f2bf(w0[i]);
    if (i < 128 * 128) g_w1[i] = f2bf(w1[i]);
    if (i < 16 * 128) {
        int n = i >> 7, k = i & 127;
        g_w2[i] = f2bf(n < 4 ? w2[((n + 1) & 3) * 128 + k] : 0.0f);
    }
    if (i < 128) { g_b0[i] = b0[i]; g_b1[i] = b1[i]; }
    if (i < 16)  g_b2p[i] = (i < 4) ? b2[(i + 1) & 3] : 0.0f;
}

// ---- bilinear sample, ONE channel (pb pre-offset by plane and channel) ------
__device__ __forceinline__ float samp1(const unsigned short* __restrict__ pb,
                                       float u, float v) {
    float x = (u + 1.0f) * 63.5f;             // align_corners=True, W=H=128
    float y = (v + 1.0f) * 63.5f;
    float xf = floorf(x), yf = floorf(y);
    float wx = x - xf, wy = y - yf;
    int x0 = (int)xf, y0 = (int)yf;
    float acc = 0.0f;
#pragma unroll
    for (int dy = 0; dy < 2; ++dy) {
        int yi = y0 + dy;
        float wyv = dy ? wy : 1.0f - wy;
        bool vy = (yi >= 0) && (yi < 128);
        int yc = yi < 0 ? 0 : (yi > 127 ? 127 : yi);
#pragma unroll
        for (int dx = 0; dx < 2; ++dx) {
            int xi = x0 + dx;
            float wv = (dx ? wx : 1.0f - wx) * wyv;
            bool vx = (xi >= 0) && (xi < 128);
            int xc = xi < 0 ? 0 : (xi > 127 ? 127 : xi);
            wv = (vx && vy) ? wv : 0.0f;
            acc += wv * __uint_as_float((unsigned)pb[(yc * 128 + xc) * C_] << 16);
        }
    }
    return acc;
}

// ---- main fused kernel: one wave per block ----------------------------------
__global__ void tri_mlp_k(const float* __restrict__ coords, float* __restrict__ out) {
    __shared__ __attribute__((aligned(16))) float hb[16 * LDS_S];  // 8448 B
    const int lane = threadIdx.x;             // 0..63
    const int l15  = lane & 15;
    const int quad = lane >> 4;
    const int ch0  = quad * 8;

    // B fragments: lane holds B[k=quad*8+j][n=l15] for each 16-col tile nt
    s8v w0f[8], w1f[4][8], w2f[4];
#pragma unroll
    for (int nt = 0; nt < 8; ++nt)
        w0f[nt] = *(const s8v*)(g_w0 + (nt * 16 + l15) * 32 + ch0);
#pragma unroll
    for (int kc = 0; kc < 4; ++kc)
#pragma unroll
        for (int nt = 0; nt < 8; ++nt)
            w1f[kc][nt] = *(const s8v*)(g_w1 + (nt * 16 + l15) * 128 + kc * 32 + ch0);
#pragma unroll
    for (int kc = 0; kc < 4; ++kc)
        w2f[kc] = *(const s8v*)(g_w2 + l15 * 128 + kc * 32 + ch0);

    float bias0[8], bias1[8];
#pragma unroll
    for (int nt = 0; nt < 8; ++nt) {
        bias0[nt] = g_b0[nt * 16 + l15];
        bias1[nt] = g_b1[nt * 16 + l15];
    }
    const float bias2 = g_b2p[l15];

    for (int tile = blockIdx.x; tile < NTILES; tile += gridDim.x) {
        // reshape-correct tile decode
        const int b  = tile >> 14;
        const int c  = (tile & 0x3FFF) >> 9;
        const int n0 = (tile & 0x1FF) << 9;
        const unsigned short* pl0 = g_planes + 0 * (HW_ * C_) + c;  // feat_xy
        const unsigned short* pl1 = g_planes + 1 * (HW_ * C_) + c;  // feat_yz
        const unsigned short* pl2 = g_planes + 2 * (HW_ * C_) + c;  // feat_xz
        const int Pb = b * 262144 + n0 + l15 * 32 + ch0;

        s8v a;
#pragma unroll
        for (int j = 0; j < 8; ++j) {
            const float* cp = coords + (size_t)(Pb + j) * 3;
            const float gx = cp[0];
            const float gy = cp[1];
            const float gz = cp[2];
            float s = samp1(pl0, gx, gy) + samp1(pl2, gx, gz) + samp1(pl1, gy, gz);
            a[j] = (short)f2bf(s);            // A[m=l15][k=ch0+j]
        }

        // layer 1: A(16x32) @ w0^T + b0 -> relu -> LDS (C layout)
        f4v c1[8];
#pragma unroll
        for (int nt = 0; nt < 8; ++nt) {
            f4v bi;
            bi[0] = bias0[nt]; bi[1] = bias0[nt]; bi[2] = bias0[nt]; bi[3] = bias0[nt];
            c1[nt] = MFMA(a, w0f[nt], bi);
        }
        __syncthreads();
#pragma unroll
        for (int nt = 0; nt < 8; ++nt)
#pragma unroll
            for (int r = 0; r < 4; ++r) {
                float v = c1[nt][r];
                hb[(quad * 4 + r) * LDS_S + nt * 16 + l15] = v > 0.0f ? v : 0.0f;
            }
        __syncthreads();
        s8v a2[4];
#pragma unroll
        for (int kc = 0; kc < 4; ++kc) {
            const float* hp = hb + l15 * LDS_S + kc * 32 + ch0;
            f4v lo = *(const f4v*)hp;
            f4v hi = *(const f4v*)(hp + 4);
            s8v t;
            t[0] = (short)f2bf(lo[0]); t[1] = (short)f2bf(lo[1]);
            t[2] = (short)f2bf(lo[2]); t[3] = (short)f2bf(lo[3]);
            t[4] = (short)f2bf(hi[0]); t[5] = (short)f2bf(hi[1]);
            t[6] = (short)f2bf(hi[2]); t[7] = (short)f2bf(hi[3]);
            a2[kc] = t;
        }

        // layer 2: h0(16x128) @ w1^T + b1 -> relu -> LDS
        f4v d[8];
#pragma unroll
        for (int nt = 0; nt < 8; ++nt) {
            d[nt][0] = bias1[nt]; d[nt][1] = bias1[nt];
            d[nt][2] = bias1[nt]; d[nt][3] = bias1[nt];
        }
#pragma unroll
        for (int kc = 0; kc < 4; ++kc)
#pragma unroll
            for (int nt = 0; nt < 8; ++nt)
                d[nt] = MFMA(a2[kc], w1f[kc][nt], d[nt]);
        __syncthreads();
#pragma unroll
        for (int nt = 0; nt < 8; ++nt)
#pragma unroll
            for (int r = 0; r < 4; ++r) {
                float v = d[nt][r];
                hb[(quad * 4 + r) * LDS_S + nt * 16 + l15] = v > 0.0f ? v : 0.0f;
            }
        __syncthreads();
        s8v a3[4];
#pragma unroll
        for (int kc = 0; kc < 4; ++kc) {
            const float* hp = hb + l15 * LDS_S + kc * 32 + ch0;
            f4v lo = *(const f4v*)hp;
            f4v hi = *(const f4v*)(hp + 4);
            s8v t;
            t[0] = (short)f2bf(lo[0]); t[1] = (short)f2bf(lo[1]);
            t[2] = (short)f2bf(lo[2]); t[3] = (short)f2bf(lo[3]);
            t[4] = (short)f2bf(hi[0]); t[5] = (short)f2bf(hi[1]);
            t[6] = (short)f2bf(hi[2]); t[7] = (short)f2bf(hi[3]);
            a3[kc] = t;
        }

        // layer 3 -> relu -> FP32 out (perm baked into g_w2/g_b2p)
        f4v o;
        o[0] = bias2; o[1] = bias2; o[2] = bias2; o[3] = bias2;
#pragma unroll
        for (int kc = 0; kc < 4; ++kc)
            o = MFMA(a3[kc], w2f[kc], o);
        if (l15 < 4) {
#pragma unroll
            for (int r = 0; r < 4; ++r) {
                float v = o[r];
                v = v > 0.0f ? v : 0.0f;
                out[(size_t)(tile * 16 + quad * 4 + r) * 4 + l15] = v;
            }
        }
    }
}

extern "C" void kernel_launch(void* const* d_in, const int* in_sizes, int n_in,
                              void* d_out, int out_size, void* d_ws, size_t ws_size,
                              hipStream_t stream) {
    const float* coords = (const float*)d_in[0];
    const float* tp = (const float*)d_in[1];
    const float* w0 = (const float*)d_in[2];
    const float* b0 = (const float*)d_in[3];
    const float* w1 = (const float*)d_in[4];
    const float* b1 = (const float*)d_in[5];
    const float* w2 = (const float*)d_in[6];
    const float* b2 = (const float*)d_in[7];
    float* out = (float*)d_out;               // FP32 output (reference dtype)

    prep_planes_k<<<6144, 256, 0, stream>>>(tp);
    prep_weights_k<<<64, 256, 0, stream>>>(w0, b0, w1, b1, w2, b2);
    tri_mlp_k<<<8192, 64, 0, stream>>>(coords, out);
}

// Round 10
// 312.924 us; speedup vs baseline: 6.8831x; 6.8831x over previous
//
#include <hip/hip_runtime.h>
#include <hip/hip_bf16.h>

// Fused triplane sample + reshape-semantics MLP (32->128->128->4, ReLU),
// FP32 out, perm [1,2,3,0] baked into w2/b2.
// One 256-thread block = 512 consecutive points of one batch = 32 MFMA tiles
// (one per channel). Phase A: sample each point ONCE (all 32 ch, 16B vector
// loads) -> S[c][n_local] in LDS. Phase B: 4 waves x 8 tiles, MFMA MLP with
// per-wave LDS transpose buffers, coalesced 256B output stores.

#define C_ 32
#define HW_ (128 * 128)
#define NPTS (4 * 262144)
#define HBS 136               /* per-wave transpose buf row stride (bf16) */

typedef short s8v __attribute__((ext_vector_type(8)));
typedef float f4v __attribute__((ext_vector_type(4)));
typedef unsigned int u4v __attribute__((ext_vector_type(4)));

__device__ __attribute__((aligned(64))) unsigned short g_planes[3 * HW_ * C_]; // (3,H,W,C) bf16
__device__ __attribute__((aligned(16))) unsigned short g_w0[128 * 32];
__device__ __attribute__((aligned(16))) unsigned short g_w1[128 * 128];
__device__ __attribute__((aligned(16))) unsigned short g_w2[16 * 128];  // perm-baked, padded
__device__ float g_b0[128];
__device__ float g_b1[128];
__device__ float g_b2p[16];

template <typename TO, typename FROM>
static __device__ __forceinline__ TO bitc(FROM f) {
    union { FROM a; TO b; } u; u.a = f; return u.b;
}

// MFMA operand-type shim (v8i16 vs v8bf16 builtin signature) -- proven.
template <typename V>
static __device__ __forceinline__ auto mfma_k32(V a, V b, f4v c, int)
    -> decltype(__builtin_amdgcn_mfma_f32_16x16x32_bf16(a, b, c, 0, 0, 0)) {
    return __builtin_amdgcn_mfma_f32_16x16x32_bf16(a, b, c, 0, 0, 0);
}
template <typename V>
static __device__ __forceinline__ f4v mfma_k32(V a, V b, f4v c, long) {
    typedef __bf16 b8v __attribute__((ext_vector_type(8)));
    return __builtin_amdgcn_mfma_f32_16x16x32_bf16(bitc<b8v>(a), bitc<b8v>(b), c, 0, 0, 0);
}
static __device__ __forceinline__ f4v MFMA(s8v a, s8v b, f4v c) {
    return mfma_k32(a, b, c, 0);
}

__device__ __forceinline__ unsigned short f2bf(float f) {
    union { float f; unsigned int i; } v; v.f = f;
    unsigned int r = v.i + 0x7FFFu + ((v.i >> 16) & 1u);
    return (unsigned short)(r >> 16);
}

// ---- prep: planes (3C,H,W) fp32 -> (3,H,W,C) bf16 ---------------------------
__global__ void prep_planes_k(const float* __restrict__ tp) {
    int o = blockIdx.x * 256 + threadIdx.x;   // 1572864 threads
    if (o >= 3 * HW_ * C_) return;
    int c  = o & 31;
    int xy = (o >> 5) & (HW_ - 1);
    int pl = o >> 19;
    g_planes[o] = f2bf(tp[(pl * C_ + c) * HW_ + xy]);
}

// ---- prep: weights/biases -> bf16; w2/b2 permuted [1,2,3,0], padded ---------
__global__ void prep_weights_k(const float* __restrict__ w0, const float* __restrict__ b0,
                               const float* __restrict__ w1, const float* __restrict__ b1,
                               const float* __restrict__ w2, const float* __restrict__ b2) {
    int i = blockIdx.x * 256 + threadIdx.x;   // 16384 threads
    if (i < 128 * 32)  g_w0[i] = f2bf(w0[i]);
    if (i < 128 * 128) g_w1[i] = f2bf(w1[i]);
    if (i < 16 * 128) {
        int n = i >> 7, k = i & 127;
        g_w2[i] = f2bf(n < 4 ? w2[((n + 1) & 3) * 128 + k] : 0.0f);
    }
    if (i < 128) { g_b0[i] = b0[i]; g_b1[i] = b1[i]; }
    if (i < 16)  g_b2p[i] = (i < 4) ? b2[(i + 1) & 3] : 0.0f;
}

// ---- bilinear sample: all 32 channels via 16B vector loads ------------------
__device__ __forceinline__ void sample_plane32(const unsigned short* __restrict__ pbase,
                                               float u, float v, float* facc) {
    float x = (u + 1.0f) * 63.5f;             // align_corners=True, W=H=128
    float y = (v + 1.0f) * 63.5f;
    float xf = floorf(x), yf = floorf(y);
    float wx = x - xf, wy = y - yf;
    int x0 = (int)xf, y0 = (int)yf;
#pragma unroll
    for (int dy = 0; dy < 2; ++dy) {
        int yi = y0 + dy;
        float wyv = dy ? wy : 1.0f - wy;
        bool vy = (yi >= 0) && (yi < 128);
        int yc = yi < 0 ? 0 : (yi > 127 ? 127 : yi);
#pragma unroll
        for (int dx = 0; dx < 2; ++dx) {
            int xi = x0 + dx;
            float wv = (dx ? wx : 1.0f - wx) * wyv;
            bool vx = (xi >= 0) && (xi < 128);
            int xc = xi < 0 ? 0 : (xi > 127 ? 127 : xi);
            wv = (vx && vy) ? wv : 0.0f;
            const u4v* cp = (const u4v*)(pbase + (yc * 128 + xc) * C_);
#pragma unroll
            for (int q = 0; q < 4; ++q) {
                u4v dw = cp[q];
#pragma unroll
                for (int jj = 0; jj < 4; ++jj) {
                    facc[q * 8 + 2 * jj]     += wv * __uint_as_float(dw[jj] << 16);
                    facc[q * 8 + 2 * jj + 1] += wv * __uint_as_float(dw[jj] & 0xFFFF0000u);
                }
            }
        }
    }
}

// ---- fused kernel -----------------------------------------------------------
__global__ __launch_bounds__(256) void fused_k(const float* __restrict__ coords,
                                               float* __restrict__ out) {
    // S[32][512] bf16 = 32768 B, then 4 per-wave transpose bufs 16*HBS bf16.
    __shared__ __attribute__((aligned(16))) unsigned short smem[16384 + 4 * 16 * HBS];
    const int tid  = threadIdx.x;             // 0..255
    const int wave = tid >> 6;                // 0..3
    const int lane = tid & 63;
    const int l15  = lane & 15;
    const int quad = lane >> 4;
    const int ch8  = quad * 8;

    const int wg = blockIdx.x;                // 0..2047
    const int b  = wg >> 9;                   // batch
    const int nb = wg & 511;                  // 512-point block within batch
    const int n0 = nb << 9;

    // ---- phase A: sample 2 points/thread, all 32 channels -> S --------------
#pragma unroll 1
    for (int pt = 0; pt < 2; ++pt) {
        const int nl = tid + pt * 256;        // n_local 0..511
        const float* cp = coords + (size_t)(b * 262144 + n0 + nl) * 3;
        const float gx = cp[0], gy = cp[1], gz = cp[2];
        float facc[32];
#pragma unroll
        for (int c = 0; c < 32; ++c) facc[c] = 0.0f;
        sample_plane32(g_planes + 0 * (HW_ * C_), gx, gy, facc);  // feat_xy
        sample_plane32(g_planes + 2 * (HW_ * C_), gx, gz, facc);  // feat_xz
        sample_plane32(g_planes + 1 * (HW_ * C_), gy, gz, facc);  // feat_yz
#pragma unroll
        for (int c = 0; c < 32; ++c)
            smem[c * 512 + nl] = f2bf(facc[c]);
    }
    __syncthreads();

    // ---- weight fragments ---------------------------------------------------
    s8v w0f[8], w1f[4][8], w2f[4];
#pragma unroll
    for (int nt = 0; nt < 8; ++nt)
        w0f[nt] = *(const s8v*)(g_w0 + (nt * 16 + l15) * 32 + ch8);
#pragma unroll
    for (int kc = 0; kc < 4; ++kc)
#pragma unroll
        for (int nt = 0; nt < 8; ++nt)
            w1f[kc][nt] = *(const s8v*)(g_w1 + (nt * 16 + l15) * 128 + kc * 32 + ch8);
#pragma unroll
    for (int kc = 0; kc < 4; ++kc)
        w2f[kc] = *(const s8v*)(g_w2 + l15 * 128 + kc * 32 + ch8);
    float bias0[8], bias1[8];
#pragma unroll
    for (int nt = 0; nt < 8; ++nt) {
        bias0[nt] = g_b0[nt * 16 + l15];
        bias1[nt] = g_b1[nt * 16 + l15];
    }
    const float bias2 = g_b2p[l15];

    unsigned short* hb = smem + 16384 + wave * (16 * HBS);  // per-wave private
    float* hbf = (float*)hb;

    // ---- phase B: 8 channel-tiles per wave ----------------------------------
#pragma unroll 1
    for (int i = 0; i < 8; ++i) {
        const int ci = wave * 8 + i;          // channel 0..31
        // A fragment: A[m=l15][k=quad*8+j] = S[ci][l15*32 + ch8 + j]
        const s8v a = *(const s8v*)(smem + ci * 512 + l15 * 32 + ch8);

        // layer 1: one nt at a time (keeps acc live-range at 1 f4v)
#pragma unroll
        for (int nt = 0; nt < 8; ++nt) {
            f4v bi;
            bi[0] = bias0[nt]; bi[1] = bias0[nt]; bi[2] = bias0[nt]; bi[3] = bias0[nt];
            f4v c1 = MFMA(a, w0f[nt], bi);
#pragma unroll
            for (int r = 0; r < 4; ++r) {
                float v = c1[r];
                hb[(quad * 4 + r) * HBS + nt * 16 + l15] = f2bf(v > 0.0f ? v : 0.0f);
            }
        }
        __builtin_amdgcn_s_waitcnt(0);
        s8v a2[4];
#pragma unroll
        for (int kc = 0; kc < 4; ++kc)
            a2[kc] = *(const s8v*)(hb + l15 * HBS + kc * 32 + ch8);

        // layer 2 in two nt-halves (d live-range 4 f4v)
#pragma unroll
        for (int half = 0; half < 2; ++half) {
            f4v d[4];
#pragma unroll
            for (int j = 0; j < 4; ++j) {
                float bv = bias1[half * 4 + j];
                d[j][0] = bv; d[j][1] = bv; d[j][2] = bv; d[j][3] = bv;
            }
#pragma unroll
            for (int kc = 0; kc < 4; ++kc)
#pragma unroll
                for (int j = 0; j < 4; ++j)
                    d[j] = MFMA(a2[kc], w1f[kc][half * 4 + j], d[j]);
#pragma unroll
            for (int j = 0; j < 4; ++j)
#pragma unroll
                for (int r = 0; r < 4; ++r) {
                    float v = d[j][r];
                    hb[(quad * 4 + r) * HBS + (half * 4 + j) * 16 + l15] =
                        f2bf(v > 0.0f ? v : 0.0f);
                }
        }
        __builtin_amdgcn_s_waitcnt(0);
        s8v a3[4];
#pragma unroll
        for (int kc = 0; kc < 4; ++kc)
            a3[kc] = *(const s8v*)(hb + l15 * HBS + kc * 32 + ch8);

        // layer 3 -> relu; C layout: row=quad*4+r, col=l15 (cols 0..3 valid)
        f4v o;
        o[0] = bias2; o[1] = bias2; o[2] = bias2; o[3] = bias2;
#pragma unroll
        for (int kc = 0; kc < 4; ++kc)
            o = MFMA(a3[kc], w2f[kc], o);

        // transpose 16x4 through LDS -> one coalesced 256B store per tile
        if (l15 < 4) {
#pragma unroll
            for (int r = 0; r < 4; ++r) {
                float v = o[r];
                hbf[(quad * 4 + r) * 4 + l15] = v > 0.0f ? v : 0.0f;
            }
        }
        __builtin_amdgcn_s_waitcnt(0);
        const int t = b * 16384 + ci * 512 + nb;   // global tile index
        if (lane < 16) {
            f4v row = *(const f4v*)(hbf + lane * 4);
            *(f4v*)(out + (size_t)(t * 16 + lane) * 4) = row;
        }
        __builtin_amdgcn_s_waitcnt(0);        // hbf reads done before next tile
    }
}

extern "C" void kernel_launch(void* const* d_in, const int* in_sizes, int n_in,
                              void* d_out, int out_size, void* d_ws, size_t ws_size,
                              hipStream_t stream) {
    const float* coords = (const float*)d_in[0];
    const float* tp = (const float*)d_in[1];
    const float* w0 = (const float*)d_in[2];
    const float* b0 = (const float*)d_in[3];
    const float* w1 = (const float*)d_in[4];
    const float* b1 = (const float*)d_in[5];
    const float* w2 = (const float*)d_in[6];
    const float* b2 = (const float*)d_in[7];
    float* out = (float*)d_out;               // FP32 output

    prep_planes_k<<<6144, 256, 0, stream>>>(tp);
    prep_weights_k<<<64, 256, 0, stream>>>(w0, b0, w1, b1, w2, b2);
    fused_k<<<2048, 256, 0, stream>>>(coords, out);
}